// Round 4
// baseline (117.808 us; speedup 1.0000x reference)
//
#include <hip/hip_runtime.h>

// Problem constants (fixed by setup_inputs): x [2,4,256,256] f32, y_ [2,1,256,256] i32
#define B_ 2
#define C_ 4
#define H_ 256
#define W_ 256
constexpr int BC    = B_ * C_;
constexpr int HW    = H_ * W_;
constexpr int NROWS = B_ * H_;                 // 512 (one block per (b,i) row)
constexpr int NTOT  = B_ * C_ * HW;            // 524288
constexpr float BIGF = (float)(H_ + W_);       // matches reference scan init

// ws control block (zeroed by hipMemsetAsync before launch):
//   f[0..7]  gS[b*4+c]   sum p*sqrt(d2) over own-channel pixels  (atomicAdd)
//   u[8..15] gM[b*4+c]   max d2 bits (atomicMax on uint, vals>=0) (atomicMax)
//   f[16]    gA          sum of (1-p_own) terms                   (atomicAdd)
//   u[17]    counter     completed-block count
struct Ctrl {
    float        gS[BC];
    unsigned int gM[BC];
    float        gA;
    unsigned int counter;
};

// ---------------------------------------------------------------------------
// Single fused kernel: one block per (b,i) image row; thread j = pixel.
// One-hot EDT fact: pixel (i,j) has d=0 for every channel except its own
// label c* (it is a zero-pixel for all c != c*). So:
//   - channels c != c*: rrw = 1, contribute sum_{c!=c*} p_c = 1 - p_{c*}
//   - channel c*: d2 >= 1, contributes p_{c*} * (-sqrt(d2)/(maxd_{c*}+eps))
// Per-block partials go to device-scope atomics; the LAST block to finish
// (counter) reads them back via atomic-RMW (coherence-safe) and writes out.
// ---------------------------------------------------------------------------
__global__ __launch_bounds__(256) void rows_kernel(
    const int* __restrict__ lab, const float* __restrict__ x,
    Ctrl* __restrict__ ctrl, float* __restrict__ out) {
    const int r = blockIdx.x;         // 0 .. NROWS-1  (= b*H + i)
    const int b = r >> 8;
    const int i = r & (H_ - 1);
    const int j = threadIdx.x;

    const int* lrow = lab + b * HW + i * W_;
    const int  c    = lrow[j];                 // own label c*

    // x loads early (independent of everything below)
    const float* xp = x + b * C_ * HW + i * W_ + j;
    const float x0 = xp[0 * HW], x1 = xp[1 * HW], x2 = xp[2 * HW], x3 = xp[3 * HW];

    // --- vertical search for own channel: nearest row with lab != c.
    // Reference defaults: no hit above -> BIG+(i+1); no hit below -> BIG+(H-i).
    const int* lcol = lab + b * HW + j;
    float gu = -1.0f, gd = -1.0f;
    for (int k = 1; gu < 0.0f || gd < 0.0f; ++k) {
        if (gu < 0.0f) {
            const int rr = i - k;
            if (rr < 0) gu = BIGF + (float)(i + 1);
            else if (lcol[rr * W_] != c) gu = (float)k;
        }
        if (gd < 0.0f) {
            const int rr = i + k;
            if (rr >= H_) gd = BIGF + (float)(H_ - i);
            else if (lcol[rr * W_] != c) gd = (float)k;
        }
    }
    const float g = fminf(gu, gd);

    // --- horizontal bounded min: g_{c*}[j'] = (lab[j']==c*) ? g[j'] : 0 ---
    __shared__ int   ls[W_];
    __shared__ float g2s[W_];
    ls[j]  = c;
    g2s[j] = g * g;
    __syncthreads();

    float best = g * g;                        // own-channel d2, >= 1 always
    for (int dj = 1; dj < W_; ++dj) {
        const float dd = (float)(dj * dj);
        if (dd >= best) break;
        const int l = j - dj, rr = j + dj;
        if (l >= 0) {
            const float v = (ls[l] == c ? g2s[l] : 0.0f) + dd;
            best = fminf(best, v);
        }
        if (rr < W_) {
            const float v = (ls[rr] == c ? g2s[rr] : 0.0f) + dd;
            best = fminf(best, v);
        }
    }

    // --- softmax over C=4 at (b,i,j) ---
    const float mx = fmaxf(fmaxf(x0, x1), fmaxf(x2, x3));
    const float e0 = __expf(x0 - mx), e1 = __expf(x1 - mx);
    const float e2 = __expf(x2 - mx), e3 = __expf(x3 - mx);
    const float s  = e0 + e1 + e2 + e3;
    const float ec = (c == 0) ? e0 : (c == 1) ? e1 : (c == 2) ? e2 : e3;
    const float pc = ec / s;

    float va = (s - ec) / s;                   // = sum_{c' != c} p_{c'}, rrw=+1
    const float psv = pc * sqrtf(best);        // scaled by -1/maxd_c at finalize
    float s0 = (c == 0) ? psv : 0.0f, s1 = (c == 1) ? psv : 0.0f;
    float s2 = (c == 2) ? psv : 0.0f, s3 = (c == 3) ? psv : 0.0f;
    float m0 = (c == 0) ? best : 0.0f, m1 = (c == 1) ? best : 0.0f;
    float m2 = (c == 2) ? best : 0.0f, m3 = (c == 3) ? best : 0.0f;

    // --- block reduce: 1 sum + 4 channel sums + 4 channel maxes ---
    #pragma unroll
    for (int off = 32; off; off >>= 1) {
        va += __shfl_down(va, off, 64);
        s0 += __shfl_down(s0, off, 64);
        s1 += __shfl_down(s1, off, 64);
        s2 += __shfl_down(s2, off, 64);
        s3 += __shfl_down(s3, off, 64);
        m0 = fmaxf(m0, __shfl_down(m0, off, 64));
        m1 = fmaxf(m1, __shfl_down(m1, off, 64));
        m2 = fmaxf(m2, __shfl_down(m2, off, 64));
        m3 = fmaxf(m3, __shfl_down(m3, off, 64));
    }
    __shared__ float lred[4][9];
    const int lane = j & 63, wid = j >> 6;
    if (lane == 0) {
        lred[wid][0] = va;
        lred[wid][1] = s0; lred[wid][2] = s1; lred[wid][3] = s2; lred[wid][4] = s3;
        lred[wid][5] = m0; lred[wid][6] = m1; lred[wid][7] = m2; lred[wid][8] = m3;
    }
    __syncthreads();
    if (j == 0) {
        float A = 0.0f, S0 = 0.0f, S1 = 0.0f, S2 = 0.0f, S3 = 0.0f;
        float M0 = 0.0f, M1 = 0.0f, M2 = 0.0f, M3 = 0.0f;
        #pragma unroll
        for (int w = 0; w < 4; ++w) {
            A  += lred[w][0];
            S0 += lred[w][1]; S1 += lred[w][2]; S2 += lred[w][3]; S3 += lred[w][4];
            M0 = fmaxf(M0, lred[w][5]); M1 = fmaxf(M1, lred[w][6]);
            M2 = fmaxf(M2, lred[w][7]); M3 = fmaxf(M3, lred[w][8]);
        }
        const int cb = b * C_;
        atomicAdd(&ctrl->gA, A);
        atomicAdd(&ctrl->gS[cb + 0], S0);
        atomicAdd(&ctrl->gS[cb + 1], S1);
        atomicAdd(&ctrl->gS[cb + 2], S2);
        atomicAdd(&ctrl->gS[cb + 3], S3);
        atomicMax(&ctrl->gM[cb + 0], __float_as_uint(M0));
        atomicMax(&ctrl->gM[cb + 1], __float_as_uint(M1));
        atomicMax(&ctrl->gM[cb + 2], __float_as_uint(M2));
        atomicMax(&ctrl->gM[cb + 3], __float_as_uint(M3));
        __threadfence();
        const unsigned int done = atomicAdd(&ctrl->counter, 1u);
        if (done == (unsigned int)(NROWS - 1)) {
            // last block: read accumulators back via atomic RMW (coherent),
            // combine: total = gA - sum_bc gS/(sqrt(gM)+1e-15); out = total/N
            float total = atomicAdd(&ctrl->gA, 0.0f);
            #pragma unroll
            for (int k = 0; k < BC; ++k) {
                const float Sk = atomicAdd(&ctrl->gS[k], 0.0f);
                const float Mk = __uint_as_float(atomicAdd(&ctrl->gM[k], 0u));
                total -= Sk / (sqrtf(Mk) + 1e-15f);
            }
            out[0] = total / (float)NTOT;
        }
    }
}

extern "C" void kernel_launch(void* const* d_in, const int* in_sizes, int n_in,
                              void* d_out, int out_size, void* d_ws, size_t ws_size,
                              hipStream_t stream) {
    const float* x = (const float*)d_in[0];   // [B,C,H,W] f32
    const int*   y = (const int*)d_in[1];     // [B,1,H,W] i32
    float* out = (float*)d_out;
    Ctrl* ctrl = (Ctrl*)d_ws;

    hipMemsetAsync(ctrl, 0, sizeof(Ctrl), stream);   // ws is poisoned 0xAA
    rows_kernel<<<NROWS, W_, 0, stream>>>(y, x, ctrl, out);
}

// Round 5
// 61.508 us; speedup vs baseline: 1.9153x; 1.9153x over previous
//
#include <hip/hip_runtime.h>

// Problem constants (fixed by setup_inputs): x [2,4,256,256] f32, y_ [2,1,256,256] i32
#define B_ 2
#define C_ 4
#define H_ 256
#define W_ 256
constexpr int BC    = B_ * C_;
constexpr int HW    = H_ * W_;
constexpr int NROWS = B_ * H_;                 // 512 (one block per (b,i) row)
constexpr int NTOT  = B_ * C_ * HW;            // 524288
constexpr float BIGF = (float)(H_ + W_);       // matches reference scan init
constexpr int PF    = 6;                       // vertical prefetch depth

// ---------------------------------------------------------------------------
// Kernel A: one block per (b,i) image row; thread j = pixel.
// One-hot EDT fact: pixel (i,j) has d=0 for every channel except its own
// label c*. So channels c != c* contribute sum p_c = 1 - p_{c*} (rrw=+1) and
// only the own channel needs a distance: p_{c*} * (-sqrt(d2)/(maxd_{c*}+eps)).
// Vertical search prefetches lab[i±1..±PF] as independent coalesced loads
// (one L2 round-trip covers ~97% of waves); rare tail loop beyond PF.
// NOTE (R4 post-mortem): do NOT fold the finalize in via device-scope
// atomics + __threadfence — cross-XCD same-line atomics cost ~45 us.
// Plain per-row partial stores + a second tiny dispatch is ~20x cheaper.
// ---------------------------------------------------------------------------
__global__ __launch_bounds__(256) void rows_kernel(
    const int* __restrict__ lab, const float* __restrict__ x,
    float* __restrict__ ps4, float* __restrict__ pm4, float* __restrict__ pa) {
    const int r = blockIdx.x;         // 0 .. NROWS-1  (= b*H + i)
    const int b = r >> 8;
    const int i = r & (H_ - 1);
    const int j = threadIdx.x;

    const int* lrow = lab + b * HW + i * W_;
    const int  c    = lrow[j];                 // own label c*

    // x loads early (independent; same memory round-trip as label prefetch)
    const float* xp = x + b * C_ * HW + i * W_ + j;
    const float x0 = xp[0 * HW], x1 = xp[1 * HW], x2 = xp[2 * HW], x3 = xp[3 * HW];

    // --- vertical search, own channel: nearest row with lab != c.
    // Reference defaults: off top -> BIG+(i+1); off bottom -> BIG+(H-i).
    const int* lcol = lab + b * HW + j;
    int lu[PF + 1], ld[PF + 1];
    #pragma unroll
    for (int k = 1; k <= PF; ++k) {            // 2*PF independent coalesced loads
        const int ru = i - k, rd = i + k;
        lu[k] = lcol[(ru >= 0 ? ru : 0) * W_];        // clamped; ignored if OOB
        ld[k] = lcol[(rd < H_ ? rd : H_ - 1) * W_];
    }
    float gu = -1.0f, gd = -1.0f;
    #pragma unroll
    for (int k = 1; k <= PF; ++k) {            // resolve in-register, in order
        if (gu < 0.0f) {
            if (i - k < 0) gu = BIGF + (float)(i + 1);
            else if (lu[k] != c) gu = (float)k;
        }
        if (gd < 0.0f) {
            if (i + k >= H_) gd = BIGF + (float)(H_ - i);
            else if (ld[k] != c) gd = (float)k;
        }
    }
    for (int k = PF + 1; gu < 0.0f || gd < 0.0f; ++k) {   // rare tail (~3% of waves)
        if (gu < 0.0f) {
            const int rr = i - k;
            if (rr < 0) gu = BIGF + (float)(i + 1);
            else if (lcol[rr * W_] != c) gu = (float)k;
        }
        if (gd < 0.0f) {
            const int rr = i + k;
            if (rr >= H_) gd = BIGF + (float)(H_ - i);
            else if (lcol[rr * W_] != c) gd = (float)k;
        }
    }
    const float g = fminf(gu, gd);

    // --- horizontal bounded min: g_{c*}[j'] = (lab[j']==c*) ? g[j'] : 0 ---
    __shared__ int   ls[W_];
    __shared__ float g2s[W_];
    ls[j]  = c;
    g2s[j] = g * g;
    __syncthreads();

    float best = g * g;                        // own-channel d2, >= 1 always
    for (int dj = 1; dj < W_; ++dj) {
        const float dd = (float)(dj * dj);
        if (dd >= best) break;
        const int l = j - dj, rr = j + dj;
        if (l >= 0) {
            const float v = (ls[l] == c ? g2s[l] : 0.0f) + dd;
            best = fminf(best, v);
        }
        if (rr < W_) {
            const float v = (ls[rr] == c ? g2s[rr] : 0.0f) + dd;
            best = fminf(best, v);
        }
    }

    // --- softmax over C=4 at (b,i,j) ---
    const float mx = fmaxf(fmaxf(x0, x1), fmaxf(x2, x3));
    const float e0 = __expf(x0 - mx), e1 = __expf(x1 - mx);
    const float e2 = __expf(x2 - mx), e3 = __expf(x3 - mx);
    const float s  = e0 + e1 + e2 + e3;
    const float ec = (c == 0) ? e0 : (c == 1) ? e1 : (c == 2) ? e2 : e3;
    const float pc = ec / s;

    float va = (s - ec) / s;                   // = sum_{c' != c} p_{c'}, rrw=+1
    const float psv = pc * sqrtf(best);        // scaled by -1/maxd_c at finalize
    float s0 = (c == 0) ? psv : 0.0f, s1 = (c == 1) ? psv : 0.0f;
    float s2 = (c == 2) ? psv : 0.0f, s3 = (c == 3) ? psv : 0.0f;
    float m0 = (c == 0) ? best : 0.0f, m1 = (c == 1) ? best : 0.0f;
    float m2 = (c == 2) ? best : 0.0f, m3 = (c == 3) ? best : 0.0f;

    // --- block reduce: 1 sum + 4 channel sums + 4 channel maxes ---
    #pragma unroll
    for (int off = 32; off; off >>= 1) {
        va += __shfl_down(va, off, 64);
        s0 += __shfl_down(s0, off, 64);
        s1 += __shfl_down(s1, off, 64);
        s2 += __shfl_down(s2, off, 64);
        s3 += __shfl_down(s3, off, 64);
        m0 = fmaxf(m0, __shfl_down(m0, off, 64));
        m1 = fmaxf(m1, __shfl_down(m1, off, 64));
        m2 = fmaxf(m2, __shfl_down(m2, off, 64));
        m3 = fmaxf(m3, __shfl_down(m3, off, 64));
    }
    __shared__ float lred[4][9];
    const int lane = j & 63, wid = j >> 6;
    if (lane == 0) {
        lred[wid][0] = va;
        lred[wid][1] = s0; lred[wid][2] = s1; lred[wid][3] = s2; lred[wid][4] = s3;
        lred[wid][5] = m0; lred[wid][6] = m1; lred[wid][7] = m2; lred[wid][8] = m3;
    }
    __syncthreads();
    if (j == 0) {
        float A = 0.0f, S0 = 0.0f, S1 = 0.0f, S2 = 0.0f, S3 = 0.0f;
        float M0 = 0.0f, M1 = 0.0f, M2 = 0.0f, M3 = 0.0f;
        #pragma unroll
        for (int w = 0; w < 4; ++w) {
            A  += lred[w][0];
            S0 += lred[w][1]; S1 += lred[w][2]; S2 += lred[w][3]; S3 += lred[w][4];
            M0 = fmaxf(M0, lred[w][5]); M1 = fmaxf(M1, lred[w][6]);
            M2 = fmaxf(M2, lred[w][7]); M3 = fmaxf(M3, lred[w][8]);
        }
        ((float4*)ps4)[r] = make_float4(S0, S1, S2, S3);
        ((float4*)pm4)[r] = make_float4(M0, M1, M2, M3);
        pa[r] = A;
    }
}

// ---------------------------------------------------------------------------
// Kernel B: ONE wave (64 threads), no LDS, no barriers. Lane t accumulates
// rows {t, t+64, t+128, t+192} (b=0) and {+256 each} (b=1) in batch-separated
// registers, then 17 shuffle-reduce chains; lane 0 combines:
//   total = A + sum_{b,c} ( -S_{b,c} / (sqrt(M_{b,c}) + 1e-15) );  out = total/N
// ---------------------------------------------------------------------------
__global__ __launch_bounds__(64) void final_kernel(
    const float4* __restrict__ ps4, const float4* __restrict__ pm4,
    const float* __restrict__ pa, float* __restrict__ out) {
    const int t = threadIdx.x;                 // 0..63
    float a = 0.0f;
    float4 sb0 = make_float4(0.f, 0.f, 0.f, 0.f), sb1 = sb0;
    float4 mb0 = sb0, mb1 = sb0;
    #pragma unroll
    for (int q = 0; q < 4; ++q) {
        const int r0 = t + q * 64;             // b = 0 rows
        const int r1 = r0 + 256;               // b = 1 rows
        a += pa[r0] + pa[r1];
        float4 v;
        v = ps4[r0]; sb0.x += v.x; sb0.y += v.y; sb0.z += v.z; sb0.w += v.w;
        v = ps4[r1]; sb1.x += v.x; sb1.y += v.y; sb1.z += v.z; sb1.w += v.w;
        v = pm4[r0]; mb0.x = fmaxf(mb0.x, v.x); mb0.y = fmaxf(mb0.y, v.y);
                     mb0.z = fmaxf(mb0.z, v.z); mb0.w = fmaxf(mb0.w, v.w);
        v = pm4[r1]; mb1.x = fmaxf(mb1.x, v.x); mb1.y = fmaxf(mb1.y, v.y);
                     mb1.z = fmaxf(mb1.z, v.z); mb1.w = fmaxf(mb1.w, v.w);
    }
    #pragma unroll
    for (int off = 32; off; off >>= 1) {
        a     += __shfl_down(a, off, 64);
        sb0.x += __shfl_down(sb0.x, off, 64); sb0.y += __shfl_down(sb0.y, off, 64);
        sb0.z += __shfl_down(sb0.z, off, 64); sb0.w += __shfl_down(sb0.w, off, 64);
        sb1.x += __shfl_down(sb1.x, off, 64); sb1.y += __shfl_down(sb1.y, off, 64);
        sb1.z += __shfl_down(sb1.z, off, 64); sb1.w += __shfl_down(sb1.w, off, 64);
        mb0.x = fmaxf(mb0.x, __shfl_down(mb0.x, off, 64));
        mb0.y = fmaxf(mb0.y, __shfl_down(mb0.y, off, 64));
        mb0.z = fmaxf(mb0.z, __shfl_down(mb0.z, off, 64));
        mb0.w = fmaxf(mb0.w, __shfl_down(mb0.w, off, 64));
        mb1.x = fmaxf(mb1.x, __shfl_down(mb1.x, off, 64));
        mb1.y = fmaxf(mb1.y, __shfl_down(mb1.y, off, 64));
        mb1.z = fmaxf(mb1.z, __shfl_down(mb1.z, off, 64));
        mb1.w = fmaxf(mb1.w, __shfl_down(mb1.w, off, 64));
    }
    if (t == 0) {
        float total = a;
        total -= sb0.x / (sqrtf(mb0.x) + 1e-15f);
        total -= sb0.y / (sqrtf(mb0.y) + 1e-15f);
        total -= sb0.z / (sqrtf(mb0.z) + 1e-15f);
        total -= sb0.w / (sqrtf(mb0.w) + 1e-15f);
        total -= sb1.x / (sqrtf(mb1.x) + 1e-15f);
        total -= sb1.y / (sqrtf(mb1.y) + 1e-15f);
        total -= sb1.z / (sqrtf(mb1.z) + 1e-15f);
        total -= sb1.w / (sqrtf(mb1.w) + 1e-15f);
        out[0] = total / (float)NTOT;
    }
}

extern "C" void kernel_launch(void* const* d_in, const int* in_sizes, int n_in,
                              void* d_out, int out_size, void* d_ws, size_t ws_size,
                              hipStream_t stream) {
    const float* x = (const float*)d_in[0];   // [B,C,H,W] f32
    const int*   y = (const int*)d_in[1];     // [B,1,H,W] i32
    float* out = (float*)d_out;

    // ws layout (16B-aligned): ps4[512*4] | pm4[512*4] | pa[512]
    float* ps4 = (float*)d_ws;
    float* pm4 = ps4 + NROWS * 4;
    float* pa  = pm4 + NROWS * 4;

    rows_kernel<<<NROWS, W_, 0, stream>>>(y, x, ps4, pm4, pa);
    final_kernel<<<1, 64, 0, stream>>>((const float4*)ps4, (const float4*)pm4, pa, out);
}